// Round 7
// baseline (263.455 us; speedup 1.0000x reference)
//
#include <hip/hip_runtime.h>
#include <hip/hip_bf16.h>
#include <stdint.h>

typedef __attribute__((ext_vector_type(4))) int i32x4;     // i8 MFMA A/B/C: 4 dwords

#define K_TOT 4096
#define N_TOT 4096

// ---------------- fused prepass: x-quant (blocks < nqb) + w-pack (rest) -------------
__global__ __launch_bounds__(512) void prep_kernel(const float4* __restrict__ x4,
                                                   unsigned int* __restrict__ xq_dw,
                                                   float* __restrict__ s_row,
                                                   int* __restrict__ qsum_row,
                                                   const int4* __restrict__ wq,
                                                   unsigned int* __restrict__ w8,
                                                   int nqb) {
    const int wave = threadIdx.x >> 6, lane = threadIdx.x & 63;
    if ((int)blockIdx.x < nqb) {
        const long row = (long)blockIdx.x * 8 + wave;
        const float4* xr = x4 + row * (K_TOT / 4);
        float4 v[16];
        float amax = 0.f;
#pragma unroll
        for (int i = 0; i < 16; ++i) {
            v[i] = xr[lane + i * 64];
            amax = fmaxf(amax, fmaxf(fmaxf(fabsf(v[i].x), fabsf(v[i].y)),
                                     fmaxf(fabsf(v[i].z), fabsf(v[i].w))));
        }
#pragma unroll
        for (int off = 32; off; off >>= 1) amax = fmaxf(amax, __shfl_xor(amax, off));
        amax = fmaxf(amax, 1e-30f);
        const float inv = 127.0f / amax;
        int qsum = 0;
        unsigned int* out = xq_dw + row * (K_TOT / 4);
#pragma unroll
        for (int i = 0; i < 16; ++i) {
            int q0 = (int)rintf(v[i].x * inv), q1 = (int)rintf(v[i].y * inv);
            int q2 = (int)rintf(v[i].z * inv), q3 = (int)rintf(v[i].w * inv);
            qsum += q0 + q1 + q2 + q3;
            out[lane + i * 64] = (unsigned int)(q0 & 255) | ((unsigned int)(q1 & 255) << 8) |
                                 ((unsigned int)(q2 & 255) << 16) | ((unsigned int)(q3 & 255) << 24);
        }
#pragma unroll
        for (int off = 32; off; off >>= 1) qsum += __shfl_xor(qsum, off);
        if (lane == 0) { s_row[row] = amax / 127.0f; qsum_row[row] = qsum; }
    } else {
        const long o = (long)((int)blockIdx.x - nqb) * 8 + wave;
        const int4* src = wq + o * (K_TOT / 4);
        unsigned int* dst = w8 + o * (K_TOT / 4);
#pragma unroll
        for (int i = 0; i < 16; ++i) {
            int4 q = src[lane + i * 64];
            dst[lane + i * 64] =
                (unsigned int)((q.x - 128) & 255) | ((unsigned int)((q.y - 128) & 255) << 8) |
                ((unsigned int)((q.z - 128) & 255) << 16) | ((unsigned int)((q.w - 128) & 255) << 24);
        }
    }
}

// ================= 256x256 4-phase i8 GEMM, B direct global->VGPR ===================
// D[M,N](i32) = Xq[M,K](i8) * W8[N,K](i8)^T via mfma_i32_16x16x64_i8.
// 8 waves (2M x 4N), per-wave 128x64; BK=64, 2 K-tiles/iter.
// A: LDS double-buffered (32 KiB), global_load_lds, chunk-XOR swizzle (<=2-way, free).
// B: global->register fragments (w8 is 16.8 MB, LLC/L2-resident; wave panel = 16
//    fully-consumed 64B lines per load), double-buffered b_ev/b_od, 2-phase lead.
// Ledger (per-thread issue order GL=A-stage, BL=B-frag):
//   P1: ds a0(buf_e) | GL(o)x2        | MFMA e q(0,*)
//   P2: ds a1(buf_e) |                | MFMA e q(1,*) | BL(e+2)x4 | vmcnt(4)
//   P3: ds a0(buf_o) | GL(e+2)x2      | MFMA o q(0,*)
//   P4: ds a1(buf_o) |                | MFMA o q(1,*) | BL(o+2)x4 | vmcnt(4)
// vmcnt(4)@P2 keeps BL(e+2): retires BL(o)+GL(o)  -> P3's ds+MFMA safe.
// vmcnt(4)@P4 keeps BL(o+2): retires BL(e+2)+GL(e+2) -> next P1 safe.

template<int MH>
__device__ __forceinline__ void read_a8(i32x4 (&a)[4], const char* Ab, int wr, int fr, int kg) {
    const int sw = (fr >> 1) & 3;
#pragma unroll
    for (int mi = 0; mi < 4; ++mi) {
        const int row = wr * 128 + (MH * 4 + mi) * 16 + fr;
        a[mi] = *(const i32x4*)(Ab + row * 64 + ((kg ^ sw) << 4));
    }
}

template<int MH>
__device__ __forceinline__ void mfma16(i32x4 (&acc)[8][4], i32x4 (&a)[4], i32x4 (&b)[4]) {
    __builtin_amdgcn_s_setprio(1);
#pragma unroll
    for (int mi = 0; mi < 4; ++mi)
#pragma unroll
        for (int ni = 0; ni < 4; ++ni)
            acc[MH * 4 + mi][ni] = __builtin_amdgcn_mfma_i32_16x16x64_i8(
                a[mi], b[ni], acc[MH * 4 + mi][ni], 0, 0, 0);
    __builtin_amdgcn_s_setprio(0);
}

#define BAR() __builtin_amdgcn_s_barrier()
#define LGKM0() asm volatile("s_waitcnt lgkmcnt(0)" ::: "memory")
#define VMCNT4() asm volatile("s_waitcnt vmcnt(4)" ::: "memory")
#define VMCNT0() asm volatile("s_waitcnt vmcnt(0)" ::: "memory")
#define FENCE() asm volatile("" ::: "memory")

__launch_bounds__(512, 1)
__global__ void gemm256_i8_kernel(const char* __restrict__ Aq,   // [M][K] i8
                                  const char* __restrict__ Bq,   // [N][K] i8
                                  const float* __restrict__ s_row,
                                  const int* __restrict__ qsum_row,
                                  const float* __restrict__ scale,
                                  const int* __restrict__ zp,
                                  const float* __restrict__ bias,
                                  float* __restrict__ C) {
    __shared__ __align__(16) char lds[2][256 * 64];   // A only, dbuf, 32 KiB

    const int nbn = N_TOT / 256;                      // 16
    int bid = blockIdx.x;
    const int nwg = gridDim.x;
    if ((nwg & 7) == 0) {                             // T1: bijective XCD swizzle
        const int cpx = nwg >> 3;
        bid = (bid & 7) * cpx + (bid >> 3);
    }
    const int bm = bid / nbn, bn = bid % nbn;

    const int tid = threadIdx.x;
    const int w = tid >> 6, lane = tid & 63;
    const int wr = w >> 2, wc = w & 3;                // 2x4 wave grid
    const int fr = lane & 15, kg = lane >> 4;         // fragment row / k-group
    const int brb = (wc >> 1) * 128 + (wc & 1) * 64;  // wave's B row base (0..255)

    const long a_row0 = (long)bm * 256;
    const long b_row0 = (long)bn * 256;

    i32x4 acc[8][4] = {};
    i32x4 afr[4], b_ev[4], b_od[4];

    // B fragment base: frag q reads global row b_row0+brb+q*16+fr, bytes t*64 + kg*16
    const char* Bg = Bq + (b_row0 + brb) * (long)K_TOT + kg * 16;
    int boff[4];
#pragma unroll
    for (int q = 0; q < 4; ++q) boff[q] = (q * 16 + fr) * K_TOT;

    auto loadB = [&](i32x4 (&b)[4], int t) {
        const char* p = Bg + t * 64;
#pragma unroll
        for (int q = 0; q < 4; ++q) b[q] = *(const i32x4*)(p + boff[q]);
    };

    // stage one A half-tile (128 rows x 64 B): 1 global_load_lds per thread.
    auto stage = [&](int t, int half) {
        char* lb = &lds[t & 1][half * 8192 + w * 1024];
        const int row = w * 16 + (lane >> 2);               // row within half
        const int c = (lane & 3) ^ (((half * 128 + row) >> 1) & 3);  // pre-swizzled chunk
        const char* g = Aq + (a_row0 + half * 128 + row) * (long)K_TOT + (long)t * 64 + c * 16;
        __builtin_amdgcn_global_load_lds(
            (const __attribute__((address_space(1))) void*)g,
            (__attribute__((address_space(3))) void*)lb, 16, 0, 0);
    };

    // prologue: GL(t0)x2 first, then BL(t0),BL(t1); vmcnt(4) retires GL(t0)+BL(t0).
    stage(0, 0); stage(0, 1);
    FENCE();
    loadB(b_ev, 0);
    loadB(b_od, 1);
    VMCNT4();
    BAR();

    const int NIT = K_TOT / 128;                      // 32 iters, 64 K-tiles
#pragma unroll 1
    for (int it = 0; it < NIT; ++it) {
        const bool nl = (it != NIT - 1);
        const int o = 2 * it + 1, e2 = 2 * it + 2, o2 = 2 * it + 3;
        const char* Ab_e = &lds[0][0];
        const char* Ab_o = &lds[1][0];

        // ---- P1: tile e q(0,*) ----
        read_a8<0>(afr, Ab_e, wr, fr, kg);
        stage(o, 0); stage(o, 1);                     // GL: A(o) -> buf1
        BAR(); LGKM0();
        mfma16<0>(acc, afr, b_ev);
        BAR();
        // ---- P2: tile e q(1,*) | BL(e+2) | vmcnt(4) ----
        read_a8<1>(afr, Ab_e, wr, fr, kg);
        BAR(); LGKM0();
        mfma16<1>(acc, afr, b_ev);
        if (nl) { loadB(b_ev, e2); VMCNT4(); } else { VMCNT0(); }
        BAR();
        // ---- P3: tile o q(0,*) ----
        read_a8<0>(afr, Ab_o, wr, fr, kg);
        if (nl) { stage(e2, 0); stage(e2, 1); }       // GL: A(e+2) -> buf0
        BAR(); LGKM0();
        mfma16<0>(acc, afr, b_od);
        BAR();
        // ---- P4: tile o q(1,*) | BL(o+2) | vmcnt(4) ----
        read_a8<1>(afr, Ab_o, wr, fr, kg);
        BAR(); LGKM0();
        mfma16<1>(acc, afr, b_od);
        if (nl) { loadB(b_od, o2); VMCNT4(); }
        BAR();
    }

    // epilogue: y = (scale[col]*s[row]) * (acc + (128-zp[col])*qsum[row]) + bias[col]
    float scs[4], c1s[4], bbs[4]; int cols[4];
#pragma unroll
    for (int n = 0; n < 4; ++n) {
        cols[n] = (int)b_row0 + brb + n * 16 + fr;
        scs[n] = scale[cols[n]];
        c1s[n] = (float)(128 - zp[cols[n]]);
        bbs[n] = bias[cols[n]];
    }
#pragma unroll
    for (int m = 0; m < 8; ++m) {
#pragma unroll
        for (int j = 0; j < 4; ++j) {
            const long r = a_row0 + wr * 128 + m * 16 + kg * 4 + j;
            const float sr = s_row[r];
            const float qs = (float)qsum_row[r];
#pragma unroll
            for (int n = 0; n < 4; ++n)
                C[r * N_TOT + cols[n]] = ((float)acc[m][n][j] + c1s[n] * qs) * (scs[n] * sr) + bbs[n];
        }
    }
}

// ---------------- fallback (ws too small / M%256!=0): fp32 tiled GEMM ----------------
__global__ void fallback_kernel(const float* __restrict__ x, const int* __restrict__ wq,
                                const int* __restrict__ zp, const float* __restrict__ sc,
                                const float* __restrict__ bs, float* __restrict__ y) {
    __shared__ float xs[32][33];
    __shared__ float ws[32][33];
    int bm = blockIdx.y, bn = blockIdx.x;
    int tid = threadIdx.x;
    int r = tid >> 5, c = tid & 31;
    float acc[4] = {0.f, 0.f, 0.f, 0.f};
    for (int k0 = 0; k0 < K_TOT; k0 += 32) {
        for (int t = tid; t < 32 * 32; t += 256) {
            int rr = t >> 5, cc = t & 31;
            xs[rr][cc] = x[(long)(bm * 32 + rr) * K_TOT + k0 + cc];
            int o = bn * 32 + rr;
            ws[rr][cc] = (float)(wq[(long)o * K_TOT + k0 + cc] - zp[o]);
        }
        __syncthreads();
#pragma unroll
        for (int kk = 0; kk < 32; ++kk) {
            float wv = ws[c][kk];
#pragma unroll
            for (int j = 0; j < 4; ++j) acc[j] += xs[r + 8 * j][kk] * wv;
        }
        __syncthreads();
    }
    int o = bn * 32 + c;
    float s = sc[o], b = bs[o];
#pragma unroll
    for (int j = 0; j < 4; ++j)
        y[(long)(bm * 32 + r + 8 * j) * N_TOT + o] = acc[j] * s + b;
}

extern "C" void kernel_launch(void* const* d_in, const int* in_sizes, int n_in,
                              void* d_out, int out_size, void* d_ws, size_t ws_size,
                              hipStream_t stream) {
    const float* x = (const float*)d_in[0];
    const int* wq = (const int*)d_in[1];
    const int* zp = (const int*)d_in[2];
    const float* sc = (const float*)d_in[3];
    const float* bs = (const float*)d_in[4];
    float* y = (float*)d_out;

    const long M = (long)in_sizes[0] / K_TOT;   // 8192

    size_t xq_bytes = (size_t)M * K_TOT;              // 33.5 MB
    size_t w8_bytes = (size_t)N_TOT * K_TOT;          // 16.8 MB
    size_t s_bytes = (size_t)M * 4;
    size_t q_bytes = (size_t)M * 4;
    size_t need = xq_bytes + w8_bytes + s_bytes + q_bytes + 256;

    if (ws_size >= need && (M & 255) == 0) {
        char* p = (char*)d_ws;
        char* xq = p;                       p += xq_bytes;
        char* w8 = p;                       p += w8_bytes;
        float* s_row = (float*)p;           p += s_bytes;
        int* qsum_row = (int*)p;

        const int nqb = (int)(M / 8);                       // 1024 quant blocks
        const int npb = N_TOT / 8;                          // 512 pack blocks
        prep_kernel<<<nqb + npb, 512, 0, stream>>>(
            (const float4*)x, (unsigned int*)xq, s_row, qsum_row,
            (const int4*)wq, (unsigned int*)w8, nqb);

        dim3 grid((unsigned)((M / 256) * (N_TOT / 256)));   // 512
        gemm256_i8_kernel<<<grid, 512, 0, stream>>>(
            xq, w8, s_row, qsum_row, sc, zp, bs, y);
    } else {
        dim3 grid(N_TOT / 32, (unsigned)(M / 32));
        fallback_kernel<<<grid, 256, 0, stream>>>(x, wq, zp, sc, bs, y);
    }
}

// Round 8
// 202.839 us; speedup vs baseline: 1.2988x; 1.2988x over previous
//
#include <hip/hip_runtime.h>
#include <hip/hip_bf16.h>
#include <stdint.h>

typedef __attribute__((ext_vector_type(4))) int i32x4;     // i8 MFMA A/B/C: 4 dwords

#define K_TOT 4096
#define N_TOT 4096

// ---------------- fused prepass: x-quant (blocks < nqb) + w-pack (rest) -------------
__global__ __launch_bounds__(512) void prep_kernel(const float4* __restrict__ x4,
                                                   unsigned int* __restrict__ xq_dw,
                                                   float* __restrict__ s_row,
                                                   int* __restrict__ qsum_row,
                                                   const int4* __restrict__ wq,
                                                   unsigned int* __restrict__ w8,
                                                   int nqb) {
    const int wave = threadIdx.x >> 6, lane = threadIdx.x & 63;
    if ((int)blockIdx.x < nqb) {
        const long row = (long)blockIdx.x * 8 + wave;
        const float4* xr = x4 + row * (K_TOT / 4);
        float4 v[16];
        float amax = 0.f;
#pragma unroll
        for (int i = 0; i < 16; ++i) {
            v[i] = xr[lane + i * 64];
            amax = fmaxf(amax, fmaxf(fmaxf(fabsf(v[i].x), fabsf(v[i].y)),
                                     fmaxf(fabsf(v[i].z), fabsf(v[i].w))));
        }
#pragma unroll
        for (int off = 32; off; off >>= 1) amax = fmaxf(amax, __shfl_xor(amax, off));
        amax = fmaxf(amax, 1e-30f);
        const float inv = 127.0f / amax;
        int qsum = 0;
        unsigned int* out = xq_dw + row * (K_TOT / 4);
#pragma unroll
        for (int i = 0; i < 16; ++i) {
            int q0 = (int)rintf(v[i].x * inv), q1 = (int)rintf(v[i].y * inv);
            int q2 = (int)rintf(v[i].z * inv), q3 = (int)rintf(v[i].w * inv);
            qsum += q0 + q1 + q2 + q3;
            out[lane + i * 64] = (unsigned int)(q0 & 255) | ((unsigned int)(q1 & 255) << 8) |
                                 ((unsigned int)(q2 & 255) << 16) | ((unsigned int)(q3 & 255) << 24);
        }
#pragma unroll
        for (int off = 32; off; off >>= 1) qsum += __shfl_xor(qsum, off);
        if (lane == 0) { s_row[row] = amax / 127.0f; qsum_row[row] = qsum; }
    } else {
        const long o = (long)((int)blockIdx.x - nqb) * 8 + wave;
        const int4* src = wq + o * (K_TOT / 4);
        unsigned int* dst = w8 + o * (K_TOT / 4);
#pragma unroll
        for (int i = 0; i < 16; ++i) {
            int4 q = src[lane + i * 64];
            dst[lane + i * 64] =
                (unsigned int)((q.x - 128) & 255) | ((unsigned int)((q.y - 128) & 255) << 8) |
                ((unsigned int)((q.z - 128) & 255) << 16) | ((unsigned int)((q.w - 128) & 255) << 24);
        }
    }
}

// ================= 256x128 4-phase i8 GEMM, 2 blocks/CU co-resident =================
// D[M,N](i32) = Xq[M,K](i8) * W8[N,K](i8)^T via mfma_i32_16x16x64_i8.
// 4 waves (2M x 2N), wave tile 128x64 (identical per-wave structure to the 256^2
// version); BK=64, 2 K-tiles/iter, LDS 48 KiB (A 16K dbuf + B 8K dbuf).
// KEY: 4-wave blocks @ ~224 regs/wave -> 8 waves/CU = TWO co-resident blocks; the
// second block's MFMA hides this block's ds_read/barrier/vmcnt stalls (cross-block
// overlap replaces the serial MFMA+LDS sum of the 1-block/CU 256^2 layout).
// Ledger (per-thread loads: A=4, B=2 per K-tile):
//   pro: A(0)4,B(0)2,B(1)2 | vmcnt(2) keeps B(1)
//   P1: ds a0,b0,b1 | stage A(o)4  | MFMA e q(0,*)
//   P2: ds a1       | stage B(e2)2 | MFMA e q(1,*) | vmcnt(2): retires A(o),B(o)... 
//       (order [B(o)2,A(o)4,B(e2)2] -> keep 2 = B(e2))
//   P3: ds a0,b0,b1 | stage A(e2)4 | MFMA o q(0,*)
//   P4: ds a1       | stage B(o2)2 | MFMA o q(1,*) | vmcnt(2): keep B(o2)
// Swizzle: LDS dest linear (global_load_lds), 16B-chunk XOR ((row>>1)&3) on global
// source and identically on ds_read -> <=2-way conflicts (free).

template<int MH>
__device__ __forceinline__ void read_a8(i32x4 (&a)[4], const char* Ab, int wr, int fr, int kg) {
    const int sw = (fr >> 1) & 3;
#pragma unroll
    for (int mi = 0; mi < 4; ++mi) {
        const int row = wr * 128 + (MH * 4 + mi) * 16 + fr;
        a[mi] = *(const i32x4*)(Ab + row * 64 + ((kg ^ sw) << 4));
    }
}

template<int NH>
__device__ __forceinline__ void read_b8(i32x4 (&b)[2], const char* Bb, int rb, int fr, int kg) {
    const int sw = (fr >> 1) & 3;
#pragma unroll
    for (int ni = 0; ni < 2; ++ni) {
        const int row = rb + (NH * 2 + ni) * 16 + fr;
        b[ni] = *(const i32x4*)(Bb + row * 64 + ((kg ^ sw) << 4));
    }
}

template<int MH, int NH>
__device__ __forceinline__ void mfma8(i32x4 (&acc)[8][4], i32x4 (&a)[4], i32x4 (&b)[2]) {
#pragma unroll
    for (int mi = 0; mi < 4; ++mi)
#pragma unroll
        for (int ni = 0; ni < 2; ++ni)
            acc[MH * 4 + mi][NH * 2 + ni] = __builtin_amdgcn_mfma_i32_16x16x64_i8(
                a[mi], b[ni], acc[MH * 4 + mi][NH * 2 + ni], 0, 0, 0);
}

#define BAR() __builtin_amdgcn_s_barrier()
#define LGKM0() asm volatile("s_waitcnt lgkmcnt(0)" ::: "memory")
#define VMCNT2() asm volatile("s_waitcnt vmcnt(2)" ::: "memory")
#define VMCNT0() asm volatile("s_waitcnt vmcnt(0)" ::: "memory")
#define PRIO1() __builtin_amdgcn_s_setprio(1)
#define PRIO0() __builtin_amdgcn_s_setprio(0)

__launch_bounds__(256, 2)
__global__ void gemm128_i8_kernel(const char* __restrict__ Aq,   // [M][K] i8
                                  const char* __restrict__ Bq,   // [N][K] i8
                                  const float* __restrict__ s_row,
                                  const int* __restrict__ qsum_row,
                                  const float* __restrict__ scale,
                                  const int* __restrict__ zp,
                                  const float* __restrict__ bias,
                                  float* __restrict__ C) {
    __shared__ __align__(16) char lds_a[2][256 * 64];   // 32 KiB (A, dbuf)
    __shared__ __align__(16) char lds_b[2][128 * 64];   // 16 KiB (B, dbuf)

    const int nbn = N_TOT / 128;                      // 32
    int bid = blockIdx.x;
    const int nwg = gridDim.x;
    if ((nwg & 7) == 0) {                             // T1: bijective XCD swizzle
        const int cpx = nwg >> 3;
        bid = (bid & 7) * cpx + (bid >> 3);
    }
    const int bm = bid / nbn, bn = bid % nbn;

    const int tid = threadIdx.x;
    const int w = tid >> 6, lane = tid & 63;
    const int wr = w >> 1, wc = w & 1;                // 2x2 wave grid
    const int fr = lane & 15, kg = lane >> 4;         // fragment row / k-group
    const int brb = wc * 64;                          // B row base (within 128-row tile)

    const long a_row0 = (long)bm * 256;
    const long b_row0 = (long)bn * 128;

    i32x4 acc[8][4] = {};
    i32x4 afr[4], b0[2], b1[2];

    // stage A tile (256 rows x 64 B = 16 KB): 4 global_load_lds per thread.
    auto stage_a = [&](int t) {
#pragma unroll
        for (int r = 0; r < 4; ++r) {
            const int j = w * 4 + r;                        // 1 KiB chunk 0..15
            char* lb = &lds_a[t & 1][j * 1024];
            const int row = j * 16 + (lane >> 2);
            const int c = (lane & 3) ^ ((row >> 1) & 3);    // pre-swizzled 16B chunk
            const char* g = Aq + (a_row0 + row) * (long)K_TOT + (long)t * 64 + c * 16;
            __builtin_amdgcn_global_load_lds(
                (const __attribute__((address_space(1))) void*)g,
                (__attribute__((address_space(3))) void*)lb, 16, 0, 0);
        }
    };
    // stage B tile (128 rows x 64 B = 8 KB): 2 global_load_lds per thread.
    auto stage_b = [&](int t) {
#pragma unroll
        for (int r = 0; r < 2; ++r) {
            const int j = w * 2 + r;                        // 1 KiB chunk 0..7
            char* lb = &lds_b[t & 1][j * 1024];
            const int row = j * 16 + (lane >> 2);
            const int c = (lane & 3) ^ ((row >> 1) & 3);
            const char* g = Bq + (b_row0 + row) * (long)K_TOT + (long)t * 64 + c * 16;
            __builtin_amdgcn_global_load_lds(
                (const __attribute__((address_space(1))) void*)g,
                (__attribute__((address_space(3))) void*)lb, 16, 0, 0);
        }
    };

    // prologue: A(0),B(0),B(1); vmcnt(2) keeps B(1).
    stage_a(0); stage_b(0); stage_b(1);
    VMCNT2();
    BAR();

    const int NIT = K_TOT / 128;                      // 32 iters, 64 K-tiles
#pragma unroll 1
    for (int it = 0; it < NIT; ++it) {
        const bool nl = (it != NIT - 1);
        const int o = 2 * it + 1, e2 = 2 * it + 2, o2 = 2 * it + 3;

        // ---- P1 (buf0, q(0,*)): ds a0,b0,b1 | stage A(o) ----
        read_a8<0>(afr, lds_a[0], wr, fr, kg);
        read_b8<0>(b0, lds_b[0], brb, fr, kg);
        read_b8<1>(b1, lds_b[0], brb, fr, kg);
        stage_a(o);
        BAR(); LGKM0();
        PRIO1(); mfma8<0, 0>(acc, afr, b0); mfma8<0, 1>(acc, afr, b1); PRIO0();
        BAR();
        // ---- P2 (buf0, q(1,*)): ds a1 | stage B(e2) | drain A(o),B(o) ----
        read_a8<1>(afr, lds_a[0], wr, fr, kg);
        if (nl) stage_b(e2);
        BAR(); LGKM0();
        PRIO1(); mfma8<1, 1>(acc, afr, b1); mfma8<1, 0>(acc, afr, b0); PRIO0();
        if (nl) { VMCNT2(); } else { VMCNT0(); }
        BAR();
        // ---- P3 (buf1, q(0,*)): ds a0,b0,b1 | stage A(e2) ----
        read_a8<0>(afr, lds_a[1], wr, fr, kg);
        read_b8<0>(b0, lds_b[1], brb, fr, kg);
        read_b8<1>(b1, lds_b[1], brb, fr, kg);
        if (nl) stage_a(e2);
        BAR(); LGKM0();
        PRIO1(); mfma8<0, 0>(acc, afr, b0); mfma8<0, 1>(acc, afr, b1); PRIO0();
        BAR();
        // ---- P4 (buf1, q(1,*)): ds a1 | stage B(o2) | drain A(e2),B(e2) ----
        read_a8<1>(afr, lds_a[1], wr, fr, kg);
        if (nl) stage_b(o2);
        BAR(); LGKM0();
        PRIO1(); mfma8<1, 1>(acc, afr, b1); mfma8<1, 0>(acc, afr, b0); PRIO0();
        if (nl) { VMCNT2(); }
        BAR();
    }

    // epilogue: y = (scale[col]*s[row]) * (acc + (128-zp[col])*qsum[row]) + bias[col]
    float scs[4], c1s[4], bbs[4]; int cols[4];
#pragma unroll
    for (int n = 0; n < 4; ++n) {
        cols[n] = (int)b_row0 + brb + n * 16 + fr;
        scs[n] = scale[cols[n]];
        c1s[n] = (float)(128 - zp[cols[n]]);
        bbs[n] = bias[cols[n]];
    }
#pragma unroll
    for (int m = 0; m < 8; ++m) {
#pragma unroll
        for (int j = 0; j < 4; ++j) {
            const long r = a_row0 + wr * 128 + m * 16 + kg * 4 + j;
            const float sr = s_row[r];
            const float qs = (float)qsum_row[r];
#pragma unroll
            for (int n = 0; n < 4; ++n)
                C[r * N_TOT + cols[n]] = ((float)acc[m][n][j] + c1s[n] * qs) * (scs[n] * sr) + bbs[n];
        }
    }
}

// ---------------- fallback (ws too small / M%256!=0): fp32 tiled GEMM ----------------
__global__ void fallback_kernel(const float* __restrict__ x, const int* __restrict__ wq,
                                const int* __restrict__ zp, const float* __restrict__ sc,
                                const float* __restrict__ bs, float* __restrict__ y) {
    __shared__ float xs[32][33];
    __shared__ float ws[32][33];
    int bm = blockIdx.y, bn = blockIdx.x;
    int tid = threadIdx.x;
    int r = tid >> 5, c = tid & 31;
    float acc[4] = {0.f, 0.f, 0.f, 0.f};
    for (int k0 = 0; k0 < K_TOT; k0 += 32) {
        for (int t = tid; t < 32 * 32; t += 256) {
            int rr = t >> 5, cc = t & 31;
            xs[rr][cc] = x[(long)(bm * 32 + rr) * K_TOT + k0 + cc];
            int o = bn * 32 + rr;
            ws[rr][cc] = (float)(wq[(long)o * K_TOT + k0 + cc] - zp[o]);
        }
        __syncthreads();
#pragma unroll
        for (int kk = 0; kk < 32; ++kk) {
            float wv = ws[c][kk];
#pragma unroll
            for (int j = 0; j < 4; ++j) acc[j] += xs[r + 8 * j][kk] * wv;
        }
        __syncthreads();
    }
    int o = bn * 32 + c;
    float s = sc[o], b = bs[o];
#pragma unroll
    for (int j = 0; j < 4; ++j)
        y[(long)(bm * 32 + r + 8 * j) * N_TOT + o] = acc[j] * s + b;
}

extern "C" void kernel_launch(void* const* d_in, const int* in_sizes, int n_in,
                              void* d_out, int out_size, void* d_ws, size_t ws_size,
                              hipStream_t stream) {
    const float* x = (const float*)d_in[0];
    const int* wq = (const int*)d_in[1];
    const int* zp = (const int*)d_in[2];
    const float* sc = (const float*)d_in[3];
    const float* bs = (const float*)d_in[4];
    float* y = (float*)d_out;

    const long M = (long)in_sizes[0] / K_TOT;   // 8192

    size_t xq_bytes = (size_t)M * K_TOT;              // 33.5 MB
    size_t w8_bytes = (size_t)N_TOT * K_TOT;          // 16.8 MB
    size_t s_bytes = (size_t)M * 4;
    size_t q_bytes = (size_t)M * 4;
    size_t need = xq_bytes + w8_bytes + s_bytes + q_bytes + 256;

    if (ws_size >= need && (M & 255) == 0) {
        char* p = (char*)d_ws;
        char* xq = p;                       p += xq_bytes;
        char* w8 = p;                       p += w8_bytes;
        float* s_row = (float*)p;           p += s_bytes;
        int* qsum_row = (int*)p;

        const int nqb = (int)(M / 8);                       // 1024 quant blocks
        const int npb = N_TOT / 8;                          // 512 pack blocks
        prep_kernel<<<nqb + npb, 512, 0, stream>>>(
            (const float4*)x, (unsigned int*)xq, s_row, qsum_row,
            (const int4*)wq, (unsigned int*)w8, nqb);

        dim3 grid((unsigned)((M / 256) * (N_TOT / 128)));   // 1024
        gemm128_i8_kernel<<<grid, 256, 0, stream>>>(
            xq, w8, s_row, qsum_row, sc, zp, bs, y);
    } else {
        dim3 grid(N_TOT / 32, (unsigned)(M / 32));
        fallback_kernel<<<grid, 256, 0, stream>>>(x, wq, zp, sc, bs, y);
    }
}